// Round 1
// baseline (2897.823 us; speedup 1.0000x reference)
//
#include <hip/hip_runtime.h>
#include <cstdint>

#define ALPHA 0.2f
#define H 256
#define EMB 64

__device__ __forceinline__ float actf(float v){ return v > 0.0f ? v : ALPHA * v; }

// ---------------- CSR build ----------------
__global__ void k_deg(const int* __restrict__ src, const int* __restrict__ dst,
                      int* __restrict__ deg_s, int* __restrict__ deg_d, int nE){
  int e = blockIdx.x * blockDim.x + threadIdx.x;
  if (e < nE){
    atomicAdd(&deg_s[src[e]], 1);
    atomicAdd(&deg_d[dst[e]], 1);
  }
}

__global__ void k_scale_off(const int* __restrict__ deg_s, const int* __restrict__ deg_d,
                            float* __restrict__ scale, int* __restrict__ off_s,
                            int* __restrict__ off_d, int* __restrict__ ctr, int nN){
  int n = blockIdx.x * blockDim.x + threadIdx.x;
  if (n < nN){
    int ds = deg_s[n];
    scale[n] = 1.0f / (1.0f + (float)ds);
    off_s[n] = atomicAdd(&ctr[0], ds);
    off_d[n] = atomicAdd(&ctr[1], deg_d[n]);
  }
}

__global__ void k_fill(const int* __restrict__ src, const int* __restrict__ dst,
                       const int* __restrict__ off_s, const int* __restrict__ off_d,
                       int* __restrict__ cur_s, int* __restrict__ cur_d,
                       int* __restrict__ nbr_s, int* __restrict__ nbr_d, int nE){
  int e = blockIdx.x * blockDim.x + threadIdx.x;
  if (e < nE){
    int s = src[e], d = dst[e];
    int p = atomicAdd(&cur_s[s], 1);
    nbr_s[off_s[s] + p] = d;          // out-neighbors of s
    int q = atomicAdd(&cur_d[d], 1);
    nbr_d[off_d[d] + q] = s;          // in-neighbors of d
  }
}

// ---------------- prenet: x = act(emb[op]@W1+b1)@W2+b2 ----------------
__global__ __launch_bounds__(256) void k_prenet(
    const float* __restrict__ emb, const int* __restrict__ op_ids,
    const float* __restrict__ W1, const float* __restrict__ b1,
    const float* __restrict__ W2, const float* __restrict__ b2,
    float* __restrict__ x){
  __shared__ float se[16][EMB];
  __shared__ float sh[16][H];
  int tid = threadIdx.x;
  long base = (long)blockIdx.x * 16;

  // stage 16 embedding rows (64 f32 each) into LDS; 256 float4 total
  for (int i = tid; i < 16 * (EMB/4); i += 256){
    int nn = i >> 4, k4 = i & 15;
    int op = op_ids[base + nn];
    ((float4*)&se[nn][0])[k4] = ((const float4*)(emb + (size_t)op * EMB))[k4];
  }
  __syncthreads();

  int j = tid;
  float acc[16];
#pragma unroll
  for (int nn = 0; nn < 16; nn++) acc[nn] = 0.f;
  for (int k0 = 0; k0 < EMB; k0 += 4){
    float w0 = W1[(k0+0)*H + j];
    float w1 = W1[(k0+1)*H + j];
    float w2 = W1[(k0+2)*H + j];
    float w3 = W1[(k0+3)*H + j];
#pragma unroll
    for (int nn = 0; nn < 16; nn++){
      float4 mv = *(const float4*)&se[nn][k0];
      acc[nn] += mv.x*w0 + mv.y*w1 + mv.z*w2 + mv.w*w3;
    }
  }
  float bb = b1[j];
#pragma unroll
  for (int nn = 0; nn < 16; nn++) sh[nn][j] = actf(acc[nn] + bb);
  __syncthreads();

#pragma unroll
  for (int nn = 0; nn < 16; nn++) acc[nn] = 0.f;
  for (int k0 = 0; k0 < H; k0 += 4){
    float w0 = W2[(k0+0)*H + j];
    float w1 = W2[(k0+1)*H + j];
    float w2 = W2[(k0+2)*H + j];
    float w3 = W2[(k0+3)*H + j];
#pragma unroll
    for (int nn = 0; nn < 16; nn++){
      float4 mv = *(const float4*)&sh[nn][k0];
      acc[nn] += mv.x*w0 + mv.y*w1 + mv.z*w2 + mv.w*w3;
    }
  }
  float b2j = b2[j];
#pragma unroll
  for (int nn = 0; nn < 16; nn++) x[(base+nn)*H + j] = acc[nn] + b2j;
}

// ---------------- aggregation: agg = (A_norm + A_norm^T + I + self terms) act(x) ----------------
// agg[n] = sum_{u in in(n)} scale[u]*act(x[u]) + scale[n]*sum_{v in out(n)} act(x[v]) + (2*scale[n]+1)*act(x[n])
__global__ __launch_bounds__(256) void k_agg(
    const float* __restrict__ x, float* __restrict__ agg, const float* __restrict__ scale,
    const int* __restrict__ off_s, const int* __restrict__ deg_s, const int* __restrict__ nbr_s,
    const int* __restrict__ off_d, const int* __restrict__ deg_d, const int* __restrict__ nbr_d,
    int nN){
  int wave = threadIdx.x >> 6;
  int lane = threadIdx.x & 63;
  int n = blockIdx.x * 4 + wave;
  if (n >= nN) return;
  const float4* xr = (const float4*)x;
  float sn = scale[n];

  float4 v = xr[(size_t)n * (H/4) + lane];
  float ax = actf(v.x), ay = actf(v.y), az = actf(v.z), aw = actf(v.w);
  float c = 2.f * sn + 1.f;
  float rx = c*ax, ry = c*ay, rz = c*az, rw = c*aw;

  // in-edges: scale[u] * act(x[u])
  int o = off_d[n], d = deg_d[n];
  for (int i = 0; i < d; i++){
    int u = nbr_d[o + i];
    float su = scale[u];
    float4 t = xr[(size_t)u * (H/4) + lane];
    rx += su * actf(t.x); ry += su * actf(t.y);
    rz += su * actf(t.z); rw += su * actf(t.w);
  }
  // out-edges: scale[n] * act(x[v])
  o = off_s[n]; d = deg_s[n];
  float ox = 0.f, oy = 0.f, oz = 0.f, ow = 0.f;
  for (int i = 0; i < d; i++){
    int u = nbr_s[o + i];
    float4 t = xr[(size_t)u * (H/4) + lane];
    ox += actf(t.x); oy += actf(t.y); oz += actf(t.z); ow += actf(t.w);
  }
  rx += sn * ox; ry += sn * oy; rz += sn * oz; rw += sn * ow;

  float4 out; out.x = rx; out.y = ry; out.z = rz; out.w = rw;
  ((float4*)agg)[(size_t)n * (H/4) + lane] = out;
}

// ---------------- GNN layer GEMM: x += act(m@W1+b1)@W2 + b2 ----------------
__global__ __launch_bounds__(256) void k_gemm(
    const float* __restrict__ m, float* __restrict__ x,
    const float* __restrict__ W1, const float* __restrict__ b1,
    const float* __restrict__ W2, const float* __restrict__ b2){
  __shared__ float sm[16][H];
  __shared__ float sh[16][H];
  int tid = threadIdx.x;
  long base = (long)blockIdx.x * 16;

  const float4* msrc = (const float4*)(m + base * H);
  float4* mdst = (float4*)&sm[0][0];
  for (int i = tid; i < 16 * (H/4); i += 256) mdst[i] = msrc[i];
  __syncthreads();

  int j = tid;
  float acc[16];
#pragma unroll
  for (int nn = 0; nn < 16; nn++) acc[nn] = 0.f;
  for (int k0 = 0; k0 < H; k0 += 4){
    float w0 = W1[(k0+0)*H + j];
    float w1 = W1[(k0+1)*H + j];
    float w2 = W1[(k0+2)*H + j];
    float w3 = W1[(k0+3)*H + j];
#pragma unroll
    for (int nn = 0; nn < 16; nn++){
      float4 mv = *(const float4*)&sm[nn][k0];
      acc[nn] += mv.x*w0 + mv.y*w1 + mv.z*w2 + mv.w*w3;
    }
  }
  float bb = b1[j];
#pragma unroll
  for (int nn = 0; nn < 16; nn++) sh[nn][j] = actf(acc[nn] + bb);
  __syncthreads();

#pragma unroll
  for (int nn = 0; nn < 16; nn++) acc[nn] = 0.f;
  for (int k0 = 0; k0 < H; k0 += 4){
    float w0 = W2[(k0+0)*H + j];
    float w1 = W2[(k0+1)*H + j];
    float w2 = W2[(k0+2)*H + j];
    float w3 = W2[(k0+3)*H + j];
#pragma unroll
    for (int nn = 0; nn < 16; nn++){
      float4 mv = *(const float4*)&sh[nn][k0];
      acc[nn] += mv.x*w0 + mv.y*w1 + mv.z*w2 + mv.w*w3;
    }
  }
  float b2j = b2[j];
#pragma unroll
  for (int nn = 0; nn < 16; nn++) x[(base+nn)*H + j] += acc[nn] + b2j;
}

// ---------------- pooling: pooled[g] += act(x[n]), graph_ids sorted ----------------
__global__ __launch_bounds__(256) void k_pool(const float* __restrict__ x,
                                              const int* __restrict__ gids,
                                              float* __restrict__ pooled, int nN){
  int j = threadIdx.x;
  int base = blockIdx.x * 256;
  if (base >= nN) return;
  int end = base + 256; if (end > nN) end = nN;
  float acc = 0.f;
  int gcur = gids[base];
  for (int n = base; n < end; n++){
    int g = gids[n];
    if (g != gcur){
      atomicAdd(&pooled[gcur*H + j], acc);
      acc = 0.f; gcur = g;
    }
    acc += actf(x[(size_t)n*H + j]);
  }
  atomicAdd(&pooled[gcur*H + j], acc);
}

// ---------------- post MLP: out[g] = act(pooled@W1+b1)@W2 + b2 ----------------
__global__ __launch_bounds__(256) void k_post(const float* __restrict__ pooled,
                                              const float* __restrict__ W1, const float* __restrict__ b1,
                                              const float* __restrict__ W2, const float* __restrict__ b2,
                                              float* __restrict__ out){
  __shared__ float sp[H];
  __shared__ float red[256];
  int g = blockIdx.x, j = threadIdx.x;
  sp[j] = pooled[g*H + j];
  __syncthreads();
  float acc = 0.f;
  for (int k = 0; k < H; k++) acc += sp[k] * W1[k*H + j];
  acc = actf(acc + b1[j]);
  red[j] = acc * W2[j];
  __syncthreads();
  for (int s = 128; s > 0; s >>= 1){
    if (j < s) red[j] += red[j + s];
    __syncthreads();
  }
  if (j == 0) out[g] = red[0] + b2[0];
}

extern "C" void kernel_launch(void* const* d_in, const int* in_sizes, int n_in,
                              void* d_out, int out_size, void* d_ws, size_t ws_size,
                              hipStream_t stream){
  const int*   op_ids = (const int*)d_in[0];
  const int*   esrc   = (const int*)d_in[1];
  const int*   edst   = (const int*)d_in[2];
  const int*   gids   = (const int*)d_in[3];
  const float* emb    = (const float*)d_in[4];
  const float* pW1    = (const float*)d_in[5];
  const float* pb1    = (const float*)d_in[6];
  const float* pW2    = (const float*)d_in[7];
  const float* pb2    = (const float*)d_in[8];
  const float* gW1    = (const float*)d_in[9];
  const float* gb1    = (const float*)d_in[10];
  const float* gW2    = (const float*)d_in[11];
  const float* gb2    = (const float*)d_in[12];
  const float* qW1    = (const float*)d_in[13];
  const float* qb1    = (const float*)d_in[14];
  const float* qW2    = (const float*)d_in[15];
  const float* qb2    = (const float*)d_in[16];

  int nN = in_sizes[0];
  int nE = in_sizes[1];
  int nG = out_size;

  char* ws = (char*)d_ws;
  size_t off = 0;
  auto alloc = [&](size_t bytes)->char* {
    char* p = ws + off;
    off += (bytes + 255) & ~(size_t)255;
    return p;
  };
  float* x     = (float*)alloc((size_t)nN * H * 4);
  float* agg   = (float*)alloc((size_t)nN * H * 4);
  float* scale = (float*)alloc((size_t)nN * 4);
  int*   nbr_s = (int*)  alloc((size_t)nE * 4);
  int*   nbr_d = (int*)  alloc((size_t)nE * 4);
  int*   off_s = (int*)  alloc((size_t)nN * 4);
  int*   off_d = (int*)  alloc((size_t)nN * 4);
  char*  zbase = ws + off;              // everything below is zeroed per call
  int*   deg_s = (int*)  alloc((size_t)nN * 4);
  int*   deg_d = (int*)  alloc((size_t)nN * 4);
  int*   cur_s = (int*)  alloc((size_t)nN * 4);
  int*   cur_d = (int*)  alloc((size_t)nN * 4);
  int*   ctr   = (int*)  alloc(256);
  float* pooled= (float*)alloc((size_t)nG * H * 4);
  size_t zbytes = (size_t)((ws + off) - zbase);

  hipMemsetAsync(zbase, 0, zbytes, stream);

  const int tb = 256;
  k_deg<<<(nE + tb - 1)/tb, tb, 0, stream>>>(esrc, edst, deg_s, deg_d, nE);
  k_scale_off<<<(nN + tb - 1)/tb, tb, 0, stream>>>(deg_s, deg_d, scale, off_s, off_d, ctr, nN);
  k_fill<<<(nE + tb - 1)/tb, tb, 0, stream>>>(esrc, edst, off_s, off_d, cur_s, cur_d, nbr_s, nbr_d, nE);

  k_prenet<<<nN/16, 256, 0, stream>>>(emb, op_ids, pW1, pb1, pW2, pb2, x);

  for (int i = 0; i < 3; i++){
    k_agg<<<nN/4, 256, 0, stream>>>(x, agg, scale,
                                    off_s, deg_s, nbr_s,
                                    off_d, deg_d, nbr_d, nN);
    k_gemm<<<nN/16, 256, 0, stream>>>(agg, x,
                                      gW1 + (size_t)i*H*H, gb1 + (size_t)i*H,
                                      gW2 + (size_t)i*H*H, gb2 + (size_t)i*H);
  }

  k_pool<<<(nN + 255)/256, 256, 0, stream>>>(x, gids, pooled, nN);
  k_post<<<nG, 256, 0, stream>>>(pooled, qW1, qb1, qW2, qb2, (float*)d_out);
}

// Round 2
// 1199.584 us; speedup vs baseline: 2.4157x; 2.4157x over previous
//
#include <hip/hip_runtime.h>
#include <cstdint>

#define ALPHA 0.2f
#define H 256

typedef __attribute__((ext_vector_type(8))) short bf16x8;
typedef __attribute__((ext_vector_type(4))) float f32x4;

__device__ __forceinline__ float actf(float v){ return v > 0.0f ? v : ALPHA * v; }

__device__ __forceinline__ ushort f2b(float f){
  union { float f; uint u; } x; x.f = f;
  uint u = x.u + 0x7FFF + ((x.u >> 16) & 1);   // RNE
  return (ushort)(u >> 16);
}
__device__ __forceinline__ float b2f(ushort h){
  union { uint u; float f; } x; x.u = (uint)h << 16; return x.f;
}

// ---------------- CSR build ----------------
__global__ void k_deg(const int* __restrict__ src, const int* __restrict__ dst,
                      int* __restrict__ deg_s, int* __restrict__ deg_d, int nE){
  int e = blockIdx.x * blockDim.x + threadIdx.x;
  if (e < nE){
    atomicAdd(&deg_s[src[e]], 1);
    atomicAdd(&deg_d[dst[e]], 1);
  }
}

__global__ void k_scale_off(const int* __restrict__ deg_s, const int* __restrict__ deg_d,
                            float* __restrict__ scale, int* __restrict__ off_s,
                            int* __restrict__ off_d, int* __restrict__ ctr, int nN){
  int n = blockIdx.x * blockDim.x + threadIdx.x;
  if (n < nN){
    int ds = deg_s[n];
    scale[n] = 1.0f / (1.0f + (float)ds);
    off_s[n] = atomicAdd(&ctr[0], ds);
    off_d[n] = atomicAdd(&ctr[1], deg_d[n]);
  }
}

__global__ void k_fill(const int* __restrict__ src, const int* __restrict__ dst,
                       const int* __restrict__ off_s, const int* __restrict__ off_d,
                       int* __restrict__ cur_s, int* __restrict__ cur_d,
                       int* __restrict__ nbr_s, int* __restrict__ nbr_d, int nE){
  int e = blockIdx.x * blockDim.x + threadIdx.x;
  if (e < nE){
    int s = src[e], d = dst[e];
    int p = atomicAdd(&cur_s[s], 1);
    nbr_s[off_s[s] + p] = d;
    int q = atomicAdd(&cur_d[d], 1);
    nbr_d[off_d[d] + q] = s;
  }
}

// ---------------- weight repack: Wt[n][k] = bf16(W[k][n]) ----------------
__global__ void k_repack(const float* __restrict__ W, ushort* __restrict__ Wt, int K, int N){
  int i = blockIdx.x * 256 + threadIdx.x;
  if (i < K * N){
    int k = i / N, n = i % N;
    Wt[(size_t)n * K + k] = f2b(W[i]);
  }
}

__global__ void k_cvt(const float* __restrict__ src, ushort* __restrict__ dst, int n){
  int i = blockIdx.x * 256 + threadIdx.x;
  if (i < n) dst[i] = f2b(src[i]);
}

// ---------------- fused 2-GEMM MLP layer (bf16 MFMA) ----------------
// y = act(A@W1+b1)@W2+b2 ; x = (RESID? x : 0) + y ; axb = bf16(act(x))
// A rows: GATHER ? embb[op_ids[row]] : aggb[row].  Wt1 [256][K1], Wt2 [256][256] bf16 (transposed).
template<int K1, bool RESID, bool GATHER>
__global__ __launch_bounds__(256) void k_fused_mlp(
    const ushort* __restrict__ Abase, const int* __restrict__ op_ids,
    const ushort* __restrict__ Wt1, const float* __restrict__ b1,
    const ushort* __restrict__ Wt2, const float* __restrict__ b2,
    float* __restrict__ x, ushort* __restrict__ axb, int nN)
{
  constexpr int LDA = K1 + 8;     // padded A stride (ushorts)
  constexpr int LDH = 264;        // padded h stride
  __shared__ ushort smem[64 * 264];   // A-tile then reused as h-tile

  const int tid = threadIdx.x;
  const long m0 = (long)blockIdx.x * 64;

  // stage A-tile: 64 rows x K1 bf16 via 16B chunks
  constexpr int CH = K1 / 8;
  for (int i = tid; i < 64 * CH; i += 256){
    int r = i / CH, c = i % CH;
    long row = m0 + r; if (row >= nN) row = nN - 1;
    const ushort* src = GATHER ? (Abase + (size_t)op_ids[row] * K1)
                               : (Abase + (size_t)row * K1);
    *(uint4*)&smem[r * LDA + c * 8] = *(const uint4*)(src + c * 8);
  }
  __syncthreads();

  const int wave = tid >> 6;
  const int lane = tid & 63;
  const int lr = lane & 15;     // A-row / B-col within frag
  const int lg = lane >> 4;     // k-group
  const int n0 = wave * 64;

  const ushort* w1r[4]; const ushort* w2r[4];
#pragma unroll
  for (int ni = 0; ni < 4; ni++){
    w1r[ni] = Wt1 + (size_t)(n0 + ni * 16 + lr) * K1;
    w2r[ni] = Wt2 + (size_t)(n0 + ni * 16 + lr) * 256;
  }

  // GEMM1: A(tile) @ W1
  f32x4 acc[4][4];
#pragma unroll
  for (int mi = 0; mi < 4; mi++)
#pragma unroll
    for (int ni = 0; ni < 4; ni++) acc[mi][ni] = (f32x4){0.f,0.f,0.f,0.f};

  for (int ks = 0; ks < K1 / 32; ks++){
    int k = ks * 32 + lg * 8;
    bf16x8 af[4], bfr[4];
#pragma unroll
    for (int mi = 0; mi < 4; mi++)
      af[mi] = *(const bf16x8*)&smem[(mi * 16 + lr) * LDA + k];
#pragma unroll
    for (int ni = 0; ni < 4; ni++)
      bfr[ni] = *(const bf16x8*)(w1r[ni] + k);
#pragma unroll
    for (int mi = 0; mi < 4; mi++)
#pragma unroll
      for (int ni = 0; ni < 4; ni++)
        acc[mi][ni] = __builtin_amdgcn_mfma_f32_16x16x32_bf16(af[mi], bfr[ni], acc[mi][ni], 0, 0, 0);
  }
  __syncthreads();   // all waves done reading A-tile

  // act + bf16 -> h-tile in LDS (same buffer)
  float bb1[4];
#pragma unroll
  for (int ni = 0; ni < 4; ni++) bb1[ni] = b1[n0 + ni * 16 + lr];
#pragma unroll
  for (int mi = 0; mi < 4; mi++)
#pragma unroll
    for (int ni = 0; ni < 4; ni++)
#pragma unroll
      for (int r = 0; r < 4; r++){
        float v = actf(acc[mi][ni][r] + bb1[ni]);
        smem[(mi * 16 + lg * 4 + r) * LDH + n0 + ni * 16 + lr] = f2b(v);
      }
  __syncthreads();

  // GEMM2: h @ W2
  f32x4 acc2[4][4];
#pragma unroll
  for (int mi = 0; mi < 4; mi++)
#pragma unroll
    for (int ni = 0; ni < 4; ni++) acc2[mi][ni] = (f32x4){0.f,0.f,0.f,0.f};

  for (int ks = 0; ks < 8; ks++){
    int k = ks * 32 + lg * 8;
    bf16x8 af[4], bfr[4];
#pragma unroll
    for (int mi = 0; mi < 4; mi++)
      af[mi] = *(const bf16x8*)&smem[(mi * 16 + lr) * LDH + k];
#pragma unroll
    for (int ni = 0; ni < 4; ni++)
      bfr[ni] = *(const bf16x8*)(w2r[ni] + k);
#pragma unroll
    for (int mi = 0; mi < 4; mi++)
#pragma unroll
      for (int ni = 0; ni < 4; ni++)
        acc2[mi][ni] = __builtin_amdgcn_mfma_f32_16x16x32_bf16(af[mi], bfr[ni], acc2[mi][ni], 0, 0, 0);
  }

  // epilogue: + b2 (+x), write x f32 and axb bf16
  float bb2[4];
#pragma unroll
  for (int ni = 0; ni < 4; ni++) bb2[ni] = b2[n0 + ni * 16 + lr];
#pragma unroll
  for (int mi = 0; mi < 4; mi++)
#pragma unroll
    for (int r = 0; r < 4; r++){
      long row = m0 + mi * 16 + lg * 4 + r;
      if (row < nN){
#pragma unroll
        for (int ni = 0; ni < 4; ni++){
          size_t idx = (size_t)row * 256 + n0 + ni * 16 + lr;
          float v = acc2[mi][ni][r] + bb2[ni];
          if (RESID) v += x[idx];
          x[idx] = v;
          axb[idx] = f2b(actf(v));
        }
      }
    }
}

// ---------------- aggregation (bf16 in / bf16 out, f32 accum) ----------------
// agg[n] = sum_in scale[u]*a[u] + scale[n]*sum_out a[v] + (2*scale[n]+1)*a[n],  a = act(x) (pre-applied)
__global__ __launch_bounds__(256) void k_agg(
    const ushort* __restrict__ axb, ushort* __restrict__ aggb, const float* __restrict__ scale,
    const int* __restrict__ off_s, const int* __restrict__ deg_s, const int* __restrict__ nbr_s,
    const int* __restrict__ off_d, const int* __restrict__ deg_d, const int* __restrict__ nbr_d,
    int nN){
  int wave = threadIdx.x >> 6;
  int lane = threadIdx.x & 63;
  int n = blockIdx.x * 4 + wave;
  if (n >= nN) return;
  const uint2* xr = (const uint2*)axb;   // 4 bf16 / lane
  float sn = scale[n];

  uint2 v = xr[(size_t)n * 64 + lane];
  float a0 = b2f((ushort)v.x), a1 = b2f((ushort)(v.x >> 16));
  float a2 = b2f((ushort)v.y), a3 = b2f((ushort)(v.y >> 16));
  float c = 2.f * sn + 1.f;
  float r0 = c * a0, r1 = c * a1, r2 = c * a2, r3 = c * a3;

  int o = off_d[n], d = deg_d[n];
  for (int i = 0; i < d; i++){
    int u = nbr_d[o + i];
    float su = scale[u];
    uint2 t = xr[(size_t)u * 64 + lane];
    r0 += su * b2f((ushort)t.x); r1 += su * b2f((ushort)(t.x >> 16));
    r2 += su * b2f((ushort)t.y); r3 += su * b2f((ushort)(t.y >> 16));
  }
  o = off_s[n]; d = deg_s[n];
  float o0 = 0.f, o1 = 0.f, o2 = 0.f, o3 = 0.f;
  for (int i = 0; i < d; i++){
    int u = nbr_s[o + i];
    uint2 t = xr[(size_t)u * 64 + lane];
    o0 += b2f((ushort)t.x); o1 += b2f((ushort)(t.x >> 16));
    o2 += b2f((ushort)t.y); o3 += b2f((ushort)(t.y >> 16));
  }
  r0 += sn * o0; r1 += sn * o1; r2 += sn * o2; r3 += sn * o3;

  uint2 out;
  out.x = (uint)f2b(r0) | ((uint)f2b(r1) << 16);
  out.y = (uint)f2b(r2) | ((uint)f2b(r3) << 16);
  ((uint2*)aggb)[(size_t)n * 64 + lane] = out;
}

// ---------------- pooling: pooled[g] += a[n]  (a = act(x) pre-applied, sorted gids) ----------------
__global__ __launch_bounds__(256) void k_pool(const ushort* __restrict__ axb,
                                              const int* __restrict__ gids,
                                              float* __restrict__ pooled, int nN){
  int j = threadIdx.x;
  int base = blockIdx.x * 256;
  if (base >= nN) return;
  int end = base + 256; if (end > nN) end = nN;
  float acc = 0.f;
  int gcur = gids[base];
  for (int n = base; n < end; n++){
    int g = gids[n];
    if (g != gcur){
      atomicAdd(&pooled[gcur * H + j], acc);
      acc = 0.f; gcur = g;
    }
    acc += b2f(axb[(size_t)n * H + j]);
  }
  atomicAdd(&pooled[gcur * H + j], acc);
}

// ---------------- post MLP ----------------
__global__ __launch_bounds__(256) void k_post(const float* __restrict__ pooled,
                                              const float* __restrict__ W1, const float* __restrict__ b1,
                                              const float* __restrict__ W2, const float* __restrict__ b2,
                                              float* __restrict__ out){
  __shared__ float sp[H];
  __shared__ float red[256];
  int g = blockIdx.x, j = threadIdx.x;
  sp[j] = pooled[g * H + j];
  __syncthreads();
  float acc = 0.f;
  for (int k = 0; k < H; k++) acc += sp[k] * W1[k * H + j];
  acc = actf(acc + b1[j]);
  red[j] = acc * W2[j];
  __syncthreads();
  for (int s = 128; s > 0; s >>= 1){
    if (j < s) red[j] += red[j + s];
    __syncthreads();
  }
  if (j == 0) out[g] = red[0] + b2[0];
}

extern "C" void kernel_launch(void* const* d_in, const int* in_sizes, int n_in,
                              void* d_out, int out_size, void* d_ws, size_t ws_size,
                              hipStream_t stream){
  const int*   op_ids = (const int*)d_in[0];
  const int*   esrc   = (const int*)d_in[1];
  const int*   edst   = (const int*)d_in[2];
  const int*   gids   = (const int*)d_in[3];
  const float* emb    = (const float*)d_in[4];
  const float* pW1    = (const float*)d_in[5];
  const float* pb1    = (const float*)d_in[6];
  const float* pW2    = (const float*)d_in[7];
  const float* pb2    = (const float*)d_in[8];
  const float* gW1    = (const float*)d_in[9];
  const float* gb1    = (const float*)d_in[10];
  const float* gW2    = (const float*)d_in[11];
  const float* gb2    = (const float*)d_in[12];
  const float* qW1    = (const float*)d_in[13];
  const float* qb1    = (const float*)d_in[14];
  const float* qW2    = (const float*)d_in[15];
  const float* qb2    = (const float*)d_in[16];

  int nN = in_sizes[0];
  int nE = in_sizes[1];
  int nG = out_size;
  int nEmb = in_sizes[4];       // 120*64

  char* ws = (char*)d_ws;
  size_t off = 0;
  auto alloc = [&](size_t bytes)->char* {
    char* p = ws + off;
    off += (bytes + 255) & ~(size_t)255;
    return p;
  };
  float*  x      = (float*) alloc((size_t)nN * H * 4);
  ushort* axb    = (ushort*)alloc((size_t)nN * H * 2);
  ushort* aggb   = (ushort*)alloc((size_t)nN * H * 2);
  float*  scale  = (float*) alloc((size_t)nN * 4);
  int*    nbr_s  = (int*)   alloc((size_t)nE * 4);
  int*    nbr_d  = (int*)   alloc((size_t)nE * 4);
  int*    off_s  = (int*)   alloc((size_t)nN * 4);
  int*    off_d  = (int*)   alloc((size_t)nN * 4);
  ushort* embb   = (ushort*)alloc((size_t)nEmb * 2);
  ushort* wtp1   = (ushort*)alloc((size_t)64 * 256 * 2);
  ushort* wtp2   = (ushort*)alloc((size_t)256 * 256 * 2);
  ushort* wtg    = (ushort*)alloc((size_t)6 * 256 * 256 * 2);  // W1[0..2],W2[0..2]
  char*   zbase  = ws + off;
  int*    deg_s  = (int*)   alloc((size_t)nN * 4);
  int*    deg_d  = (int*)   alloc((size_t)nN * 4);
  int*    cur_s  = (int*)   alloc((size_t)nN * 4);
  int*    cur_d  = (int*)   alloc((size_t)nN * 4);
  int*    ctr    = (int*)   alloc(256);
  float*  pooled = (float*) alloc((size_t)nG * H * 4);
  size_t zbytes = (size_t)((ws + off) - zbase);

  hipMemsetAsync(zbase, 0, zbytes, stream);

  const int tb = 256;
  k_deg<<<(nE + tb - 1)/tb, tb, 0, stream>>>(esrc, edst, deg_s, deg_d, nE);
  k_scale_off<<<(nN + tb - 1)/tb, tb, 0, stream>>>(deg_s, deg_d, scale, off_s, off_d, ctr, nN);
  k_fill<<<(nE + tb - 1)/tb, tb, 0, stream>>>(esrc, edst, off_s, off_d, cur_s, cur_d, nbr_s, nbr_d, nE);

  // weight prep
  k_cvt<<<(nEmb + 255)/256, 256, 0, stream>>>(emb, embb, nEmb);
  k_repack<<<(64*256 + 255)/256, 256, 0, stream>>>(pW1, wtp1, 64, 256);
  k_repack<<<(256*256 + 255)/256, 256, 0, stream>>>(pW2, wtp2, 256, 256);
  for (int i = 0; i < 3; i++){
    k_repack<<<(256*256 + 255)/256, 256, 0, stream>>>(gW1 + (size_t)i*256*256, wtg + (size_t)(2*i)*256*256, 256, 256);
    k_repack<<<(256*256 + 255)/256, 256, 0, stream>>>(gW2 + (size_t)i*256*256, wtg + (size_t)(2*i+1)*256*256, 256, 256);
  }

  int gblk = (nN + 63) / 64;
  // prenet: x = act(emb[op]@W1+b1)@W2+b2
  k_fused_mlp<64, false, true><<<gblk, 256, 0, stream>>>(
      embb, op_ids, wtp1, pb1, wtp2, pb2, x, axb, nN);

  for (int i = 0; i < 3; i++){
    k_agg<<<(nN + 3)/4, 256, 0, stream>>>(axb, aggb, scale,
                                          off_s, deg_s, nbr_s,
                                          off_d, deg_d, nbr_d, nN);
    k_fused_mlp<256, true, false><<<gblk, 256, 0, stream>>>(
        aggb, op_ids, wtg + (size_t)(2*i)*256*256, gb1 + (size_t)i*H,
        wtg + (size_t)(2*i+1)*256*256, gb2 + (size_t)i*H, x, axb, nN);
  }

  k_pool<<<(nN + 255)/256, 256, 0, stream>>>(axb, gids, pooled, nN);
  k_post<<<nG, 256, 0, stream>>>(pooled, qW1, qb1, qW2, qb2, (float*)d_out);
}

// Round 3
// 1037.244 us; speedup vs baseline: 2.7938x; 1.1565x over previous
//
#include <hip/hip_runtime.h>
#include <cstdint>

#define ALPHA 0.2f
#define H 256

typedef __attribute__((ext_vector_type(8))) short bf16x8;
typedef __attribute__((ext_vector_type(4))) float f32x4;

__device__ __forceinline__ float actf(float v){ return v > 0.0f ? v : ALPHA * v; }

__device__ __forceinline__ ushort f2b(float f){
  union { float f; uint u; } x; x.f = f;
  uint u = x.u + 0x7FFF + ((x.u >> 16) & 1);   // RNE
  return (ushort)(u >> 16);
}
__device__ __forceinline__ float b2f(ushort h){
  union { uint u; float f; } x; x.u = (uint)h << 16; return x.f;
}

// ---------------- CSR build (combined weighted neighbor list) ----------------
// Edge (s->d) contributes entry (nbr=s, w=scale[s]) at node d (in-edge)
//                     and entry (nbr=d, w=scale[s]) at node s (out-edge).
__global__ void k_deg(const int* __restrict__ src, const int* __restrict__ dst,
                      int* __restrict__ deg_s, int* __restrict__ deg_t, int nE){
  int e = blockIdx.x * blockDim.x + threadIdx.x;
  if (e < nE){
    atomicAdd(&deg_s[src[e]], 1);
    atomicAdd(&deg_t[src[e]], 1);
    atomicAdd(&deg_t[dst[e]], 1);
  }
}

__global__ void k_scale_off(const int* __restrict__ deg_s, const int* __restrict__ deg_t,
                            float* __restrict__ scale, int* __restrict__ off_t,
                            int* __restrict__ ctr, int nN){
  int n = blockIdx.x * blockDim.x + threadIdx.x;
  if (n < nN){
    scale[n] = 1.0f / (1.0f + (float)deg_s[n]);
    off_t[n] = atomicAdd(&ctr[0], deg_t[n]);
  }
}

__global__ void k_fill(const int* __restrict__ src, const int* __restrict__ dst,
                       const float* __restrict__ scale,
                       const int* __restrict__ off_t, int* __restrict__ cur,
                       int* __restrict__ nbr_all, float* __restrict__ wgt_all, int nE){
  int e = blockIdx.x * blockDim.x + threadIdx.x;
  if (e < nE){
    int s = src[e], d = dst[e];
    float w = scale[s];
    int p = atomicAdd(&cur[d], 1);
    int idx = off_t[d] + p;
    nbr_all[idx] = s; wgt_all[idx] = w;
    int q = atomicAdd(&cur[s], 1);
    idx = off_t[s] + q;
    nbr_all[idx] = d; wgt_all[idx] = w;
  }
}

// ---------------- weight repack: Wt[n][k] = bf16(W[k][n]) ----------------
__global__ void k_repack(const float* __restrict__ W, ushort* __restrict__ Wt, int K, int N){
  int i = blockIdx.x * 256 + threadIdx.x;
  if (i < K * N){
    int k = i / N, n = i % N;
    Wt[(size_t)n * K + k] = f2b(W[i]);
  }
}

__global__ void k_cvt(const float* __restrict__ src, ushort* __restrict__ dst, int n){
  int i = blockIdx.x * 256 + threadIdx.x;
  if (i < n) dst[i] = f2b(src[i]);
}

// ---------------- fused 2-GEMM MLP layer (bf16 MFMA) ----------------
template<int K1, bool RESID, bool GATHER>
__global__ __launch_bounds__(256) void k_fused_mlp(
    const ushort* __restrict__ Abase, const int* __restrict__ op_ids,
    const ushort* __restrict__ Wt1, const float* __restrict__ b1,
    const ushort* __restrict__ Wt2, const float* __restrict__ b2,
    float* __restrict__ x, ushort* __restrict__ axb, int nN)
{
  constexpr int LDA = K1 + 8;
  constexpr int LDH = 264;
  __shared__ ushort smem[64 * 264];

  const int tid = threadIdx.x;
  const long m0 = (long)blockIdx.x * 64;

  constexpr int CH = K1 / 8;
  for (int i = tid; i < 64 * CH; i += 256){
    int r = i / CH, c = i % CH;
    long row = m0 + r; if (row >= nN) row = nN - 1;
    const ushort* src = GATHER ? (Abase + (size_t)op_ids[row] * K1)
                               : (Abase + (size_t)row * K1);
    *(uint4*)&smem[r * LDA + c * 8] = *(const uint4*)(src + c * 8);
  }
  __syncthreads();

  const int wave = tid >> 6;
  const int lane = tid & 63;
  const int lr = lane & 15;
  const int lg = lane >> 4;
  const int n0 = wave * 64;

  const ushort* w1r[4]; const ushort* w2r[4];
#pragma unroll
  for (int ni = 0; ni < 4; ni++){
    w1r[ni] = Wt1 + (size_t)(n0 + ni * 16 + lr) * K1;
    w2r[ni] = Wt2 + (size_t)(n0 + ni * 16 + lr) * 256;
  }

  f32x4 acc[4][4];
#pragma unroll
  for (int mi = 0; mi < 4; mi++)
#pragma unroll
    for (int ni = 0; ni < 4; ni++) acc[mi][ni] = (f32x4){0.f,0.f,0.f,0.f};

  for (int ks = 0; ks < K1 / 32; ks++){
    int k = ks * 32 + lg * 8;
    bf16x8 af[4], bfr[4];
#pragma unroll
    for (int mi = 0; mi < 4; mi++)
      af[mi] = *(const bf16x8*)&smem[(mi * 16 + lr) * LDA + k];
#pragma unroll
    for (int ni = 0; ni < 4; ni++)
      bfr[ni] = *(const bf16x8*)(w1r[ni] + k);
#pragma unroll
    for (int mi = 0; mi < 4; mi++)
#pragma unroll
      for (int ni = 0; ni < 4; ni++)
        acc[mi][ni] = __builtin_amdgcn_mfma_f32_16x16x32_bf16(af[mi], bfr[ni], acc[mi][ni], 0, 0, 0);
  }
  __syncthreads();

  float bb1[4];
#pragma unroll
  for (int ni = 0; ni < 4; ni++) bb1[ni] = b1[n0 + ni * 16 + lr];
#pragma unroll
  for (int mi = 0; mi < 4; mi++)
#pragma unroll
    for (int ni = 0; ni < 4; ni++)
#pragma unroll
      for (int r = 0; r < 4; r++){
        float v = actf(acc[mi][ni][r] + bb1[ni]);
        smem[(mi * 16 + lg * 4 + r) * LDH + n0 + ni * 16 + lr] = f2b(v);
      }
  __syncthreads();

  f32x4 acc2[4][4];
#pragma unroll
  for (int mi = 0; mi < 4; mi++)
#pragma unroll
    for (int ni = 0; ni < 4; ni++) acc2[mi][ni] = (f32x4){0.f,0.f,0.f,0.f};

  for (int ks = 0; ks < 8; ks++){
    int k = ks * 32 + lg * 8;
    bf16x8 af[4], bfr[4];
#pragma unroll
    for (int mi = 0; mi < 4; mi++)
      af[mi] = *(const bf16x8*)&smem[(mi * 16 + lr) * LDH + k];
#pragma unroll
    for (int ni = 0; ni < 4; ni++)
      bfr[ni] = *(const bf16x8*)(w2r[ni] + k);
#pragma unroll
    for (int mi = 0; mi < 4; mi++)
#pragma unroll
      for (int ni = 0; ni < 4; ni++)
        acc2[mi][ni] = __builtin_amdgcn_mfma_f32_16x16x32_bf16(af[mi], bfr[ni], acc2[mi][ni], 0, 0, 0);
  }

  float bb2[4];
#pragma unroll
  for (int ni = 0; ni < 4; ni++) bb2[ni] = b2[n0 + ni * 16 + lr];
#pragma unroll
  for (int mi = 0; mi < 4; mi++)
#pragma unroll
    for (int r = 0; r < 4; r++){
      long row = m0 + mi * 16 + lg * 4 + r;
      if (row < nN){
#pragma unroll
        for (int ni = 0; ni < 4; ni++){
          size_t idx = (size_t)row * 256 + n0 + ni * 16 + lr;
          float v = acc2[mi][ni][r] + bb2[ni];
          if (RESID) v += x[idx];
          x[idx] = v;
          axb[idx] = f2b(actf(v));
        }
      }
    }
}

// ---------------- aggregation: single weighted-neighbor loop, unroll x8 ----------------
// agg[n] = sum_i w_i * a[nbr_i] + (2*scale[n]+1) * a[n]
__global__ __launch_bounds__(256) void k_agg(
    const ushort* __restrict__ axb, ushort* __restrict__ aggb, const float* __restrict__ scale,
    const int* __restrict__ off_t, const int* __restrict__ deg_t,
    const int* __restrict__ nbr_all, const float* __restrict__ wgt_all, int nN){
  int wave = threadIdx.x >> 6;
  int lane = threadIdx.x & 63;
  int n = blockIdx.x * 4 + wave;
  if (n >= nN) return;
  const uint2* xr = (const uint2*)axb;
  float sn = scale[n];

  uint2 v = xr[(size_t)n * 64 + lane];
  float c = 2.f * sn + 1.f;
  float r0 = c * b2f((ushort)v.x), r1 = c * b2f((ushort)(v.x >> 16));
  float r2 = c * b2f((ushort)v.y), r3 = c * b2f((ushort)(v.y >> 16));

  const int o = off_t[n], d = deg_t[n];
  int i = 0;
  for (; i + 8 <= d; i += 8){
    int u[8]; float w[8];
#pragma unroll
    for (int j = 0; j < 8; j++){ u[j] = nbr_all[o + i + j]; w[j] = wgt_all[o + i + j]; }
    uint2 t[8];
#pragma unroll
    for (int j = 0; j < 8; j++) t[j] = xr[(size_t)u[j] * 64 + lane];
#pragma unroll
    for (int j = 0; j < 8; j++){
      r0 += w[j] * b2f((ushort)t[j].x); r1 += w[j] * b2f((ushort)(t[j].x >> 16));
      r2 += w[j] * b2f((ushort)t[j].y); r3 += w[j] * b2f((ushort)(t[j].y >> 16));
    }
  }
  for (; i < d; i++){
    int u = nbr_all[o + i]; float w = wgt_all[o + i];
    uint2 t = xr[(size_t)u * 64 + lane];
    r0 += w * b2f((ushort)t.x); r1 += w * b2f((ushort)(t.x >> 16));
    r2 += w * b2f((ushort)t.y); r3 += w * b2f((ushort)(t.y >> 16));
  }

  uint2 out;
  out.x = (uint)f2b(r0) | ((uint)f2b(r1) << 16);
  out.y = (uint)f2b(r2) | ((uint)f2b(r3) << 16);
  ((uint2*)aggb)[(size_t)n * 64 + lane] = out;
}

// ---------------- pooling ----------------
__global__ __launch_bounds__(256) void k_pool(const ushort* __restrict__ axb,
                                              const int* __restrict__ gids,
                                              float* __restrict__ pooled, int nN){
  int j = threadIdx.x;
  int base = blockIdx.x * 256;
  if (base >= nN) return;
  int end = base + 256; if (end > nN) end = nN;
  float acc = 0.f;
  int gcur = gids[base];
  for (int n = base; n < end; n++){
    int g = gids[n];
    if (g != gcur){
      atomicAdd(&pooled[gcur * H + j], acc);
      acc = 0.f; gcur = g;
    }
    acc += b2f(axb[(size_t)n * H + j]);
  }
  atomicAdd(&pooled[gcur * H + j], acc);
}

// ---------------- post MLP ----------------
__global__ __launch_bounds__(256) void k_post(const float* __restrict__ pooled,
                                              const float* __restrict__ W1, const float* __restrict__ b1,
                                              const float* __restrict__ W2, const float* __restrict__ b2,
                                              float* __restrict__ out){
  __shared__ float sp[H];
  __shared__ float red[256];
  int g = blockIdx.x, j = threadIdx.x;
  sp[j] = pooled[g * H + j];
  __syncthreads();
  float acc = 0.f;
  for (int k = 0; k < H; k++) acc += sp[k] * W1[k * H + j];
  acc = actf(acc + b1[j]);
  red[j] = acc * W2[j];
  __syncthreads();
  for (int s = 128; s > 0; s >>= 1){
    if (j < s) red[j] += red[j + s];
    __syncthreads();
  }
  if (j == 0) out[g] = red[0] + b2[0];
}

extern "C" void kernel_launch(void* const* d_in, const int* in_sizes, int n_in,
                              void* d_out, int out_size, void* d_ws, size_t ws_size,
                              hipStream_t stream){
  const int*   op_ids = (const int*)d_in[0];
  const int*   esrc   = (const int*)d_in[1];
  const int*   edst   = (const int*)d_in[2];
  const int*   gids   = (const int*)d_in[3];
  const float* emb    = (const float*)d_in[4];
  const float* pW1    = (const float*)d_in[5];
  const float* pb1    = (const float*)d_in[6];
  const float* pW2    = (const float*)d_in[7];
  const float* pb2    = (const float*)d_in[8];
  const float* gW1    = (const float*)d_in[9];
  const float* gb1    = (const float*)d_in[10];
  const float* gW2    = (const float*)d_in[11];
  const float* gb2    = (const float*)d_in[12];
  const float* qW1    = (const float*)d_in[13];
  const float* qb1    = (const float*)d_in[14];
  const float* qW2    = (const float*)d_in[15];
  const float* qb2    = (const float*)d_in[16];

  int nN = in_sizes[0];
  int nE = in_sizes[1];
  int nG = out_size;
  int nEmb = in_sizes[4];

  char* ws = (char*)d_ws;
  size_t off = 0;
  auto alloc = [&](size_t bytes)->char* {
    char* p = ws + off;
    off += (bytes + 255) & ~(size_t)255;
    return p;
  };
  float*  x       = (float*) alloc((size_t)nN * H * 4);
  ushort* axb     = (ushort*)alloc((size_t)nN * H * 2);
  ushort* aggb    = (ushort*)alloc((size_t)nN * H * 2);
  float*  scale   = (float*) alloc((size_t)nN * 4);
  int*    nbr_all = (int*)   alloc((size_t)2 * nE * 4);
  float*  wgt_all = (float*) alloc((size_t)2 * nE * 4);
  int*    off_t   = (int*)   alloc((size_t)nN * 4);
  ushort* embb    = (ushort*)alloc((size_t)nEmb * 2);
  ushort* wtp1    = (ushort*)alloc((size_t)64 * 256 * 2);
  ushort* wtp2    = (ushort*)alloc((size_t)256 * 256 * 2);
  ushort* wtg     = (ushort*)alloc((size_t)6 * 256 * 256 * 2);
  char*   zbase   = ws + off;
  int*    deg_s   = (int*)   alloc((size_t)nN * 4);
  int*    deg_t   = (int*)   alloc((size_t)nN * 4);
  int*    cur     = (int*)   alloc((size_t)nN * 4);
  int*    ctr     = (int*)   alloc(256);
  float*  pooled  = (float*) alloc((size_t)nG * H * 4);
  size_t zbytes = (size_t)((ws + off) - zbase);

  hipMemsetAsync(zbase, 0, zbytes, stream);

  const int tb = 256;
  k_deg<<<(nE + tb - 1)/tb, tb, 0, stream>>>(esrc, edst, deg_s, deg_t, nE);
  k_scale_off<<<(nN + tb - 1)/tb, tb, 0, stream>>>(deg_s, deg_t, scale, off_t, ctr, nN);
  k_fill<<<(nE + tb - 1)/tb, tb, 0, stream>>>(esrc, edst, scale, off_t, cur, nbr_all, wgt_all, nE);

  k_cvt<<<(nEmb + 255)/256, 256, 0, stream>>>(emb, embb, nEmb);
  k_repack<<<(64*256 + 255)/256, 256, 0, stream>>>(pW1, wtp1, 64, 256);
  k_repack<<<(256*256 + 255)/256, 256, 0, stream>>>(pW2, wtp2, 256, 256);
  for (int i = 0; i < 3; i++){
    k_repack<<<(256*256 + 255)/256, 256, 0, stream>>>(gW1 + (size_t)i*256*256, wtg + (size_t)(2*i)*256*256, 256, 256);
    k_repack<<<(256*256 + 255)/256, 256, 0, stream>>>(gW2 + (size_t)i*256*256, wtg + (size_t)(2*i+1)*256*256, 256, 256);
  }

  int gblk = (nN + 63) / 64;
  k_fused_mlp<64, false, true><<<gblk, 256, 0, stream>>>(
      embb, op_ids, wtp1, pb1, wtp2, pb2, x, axb, nN);

  for (int i = 0; i < 3; i++){
    k_agg<<<(nN + 3)/4, 256, 0, stream>>>(axb, aggb, scale, off_t, deg_t, nbr_all, wgt_all, nN);
    k_fused_mlp<256, true, false><<<gblk, 256, 0, stream>>>(
        aggb, op_ids, wtg + (size_t)(2*i)*256*256, gb1 + (size_t)i*H,
        wtg + (size_t)(2*i+1)*256*256, gb2 + (size_t)i*H, x, axb, nN);
  }

  k_pool<<<(nN + 255)/256, 256, 0, stream>>>(axb, gids, pooled, nN);
  k_post<<<nG, 256, 0, stream>>>(pooled, qW1, qb1, qW2, qb2, (float*)d_out);
}

// Round 4
// 1036.464 us; speedup vs baseline: 2.7959x; 1.0008x over previous
//
#include <hip/hip_runtime.h>
#include <cstdint>

#define ALPHA 0.2f
#define H 256

typedef __attribute__((ext_vector_type(8))) short bf16x8;
typedef __attribute__((ext_vector_type(4))) float f32x4;

__device__ __forceinline__ float actf(float v){ return v > 0.0f ? v : ALPHA * v; }

__device__ __forceinline__ ushort f2b(float f){
  union { float f; uint u; } x; x.f = f;
  uint u = x.u + 0x7FFF + ((x.u >> 16) & 1);   // RNE
  return (ushort)(u >> 16);
}
__device__ __forceinline__ float b2f(ushort h){
  union { uint u; float f; } x; x.u = (uint)h << 16; return x.f;
}

__device__ __forceinline__ void gld_lds16(const void* g, void* l){
  __builtin_amdgcn_global_load_lds((const __attribute__((address_space(1))) void*)g,
                                   (__attribute__((address_space(3))) void*)l, 16, 0, 0);
}

// ---------------- CSR build (combined weighted neighbor list) ----------------
__global__ void k_deg(const int* __restrict__ src, const int* __restrict__ dst,
                      int* __restrict__ deg_s, int* __restrict__ deg_t, int nE){
  int e = blockIdx.x * blockDim.x + threadIdx.x;
  if (e < nE){
    atomicAdd(&deg_s[src[e]], 1);
    atomicAdd(&deg_t[src[e]], 1);
    atomicAdd(&deg_t[dst[e]], 1);
  }
}

__global__ void k_scale_off(const int* __restrict__ deg_s, const int* __restrict__ deg_t,
                            float* __restrict__ scale, int* __restrict__ off_t,
                            int* __restrict__ ctr, int nN){
  int n = blockIdx.x * blockDim.x + threadIdx.x;
  if (n < nN){
    scale[n] = 1.0f / (1.0f + (float)deg_s[n]);
    off_t[n] = atomicAdd(&ctr[0], deg_t[n]);
  }
}

__global__ void k_fill(const int* __restrict__ src, const int* __restrict__ dst,
                       const float* __restrict__ scale,
                       const int* __restrict__ off_t, int* __restrict__ cur,
                       int* __restrict__ nbr_all, float* __restrict__ wgt_all, int nE){
  int e = blockIdx.x * blockDim.x + threadIdx.x;
  if (e < nE){
    int s = src[e], d = dst[e];
    float w = scale[s];
    int p = atomicAdd(&cur[d], 1);
    int idx = off_t[d] + p;
    nbr_all[idx] = s; wgt_all[idx] = w;
    int q = atomicAdd(&cur[s], 1);
    idx = off_t[s] + q;
    nbr_all[idx] = d; wgt_all[idx] = w;
  }
}

// ---------------- weight repack: Wt[n][k] = bf16(W[k][n]) ----------------
__global__ void k_repack(const float* __restrict__ W, ushort* __restrict__ Wt, int K, int N){
  int i = blockIdx.x * 256 + threadIdx.x;
  if (i < K * N){
    int k = i / N, n = i % N;
    Wt[(size_t)n * K + k] = f2b(W[i]);
  }
}

__global__ void k_cvt(const float* __restrict__ src, ushort* __restrict__ dst, int n){
  int i = blockIdx.x * 256 + threadIdx.x;
  if (i < n) dst[i] = f2b(src[i]);
}

// ---------------- fused 2-GEMM MLP layer (bf16 MFMA, swizzled 32KB LDS) ----------------
// LDS layout: semantic [64][K] ushort, stored at ushort-index  idx ^ ((row&7)<<3)
// (byte-bit-4..6 XOR with row&7). Staged by global_load_lds with inverse-swizzled src.
template<int K1, bool RESID, bool GATHER>
__global__ __launch_bounds__(256) void k_fused_mlp(
    const ushort* __restrict__ Abase, const int* __restrict__ op_ids,
    const ushort* __restrict__ Wt1, const float* __restrict__ b1,
    const ushort* __restrict__ Wt2, const float* __restrict__ b2,
    float* __restrict__ x, ushort* __restrict__ axb, int nN)
{
  __shared__ ushort smem[64 * 256];    // 32 KiB exactly -> 5 blocks/CU

  const int tid = threadIdx.x;
  const long m0 = (long)blockIdx.x * 64;

  // ---- stage A-tile: 64 rows x K1 bf16 via global_load_lds (16B), swizzled src ----
  {
    constexpr int ROWB = K1 * 2;                 // bytes per row
    constexpr int ROUNDS = (64 * ROWB) / 4096;   // 256 threads x 16 B per round
    char* lds_c = (char*)smem;
#pragma unroll
    for (int rr = 0; rr < ROUNDS; rr++){
      int b = rr * 4096 + tid * 16;              // linear LDS byte offset
      int row = b / ROWB;
      int colb = b % ROWB;
      long rg = m0 + row; if (rg >= nN) rg = nN - 1;
      long srow = GATHER ? (long)op_ids[rg] : rg;
      const char* src = (const char*)Abase + srow * ROWB + (colb ^ ((row & 7) << 4));
      gld_lds16(src, lds_c + b);
    }
  }
  __syncthreads();   // drains vmcnt(0): LDS tile ready

  const int wave = tid >> 6;
  const int lane = tid & 63;
  const int lr = lane & 15;
  const int lg = lane >> 4;
  const int n0 = wave * 64;
  const int aswz = (lr & 7) << 3;     // read-side swizzle (row&7 == lr&7)

  const ushort* w1r[4]; const ushort* w2r[4];
#pragma unroll
  for (int ni = 0; ni < 4; ni++){
    w1r[ni] = Wt1 + (size_t)(n0 + ni * 16 + lr) * K1;
    w2r[ni] = Wt2 + (size_t)(n0 + ni * 16 + lr) * 256;
  }

  // ---- GEMM1: A @ W1 ----
  f32x4 acc[4][4];
#pragma unroll
  for (int mi = 0; mi < 4; mi++)
#pragma unroll
    for (int ni = 0; ni < 4; ni++) acc[mi][ni] = (f32x4){0.f,0.f,0.f,0.f};

  for (int ks = 0; ks < K1 / 32; ks++){
    int k = ks * 32 + lg * 8;
    bf16x8 af[4], bfr[4];
#pragma unroll
    for (int mi = 0; mi < 4; mi++){
      int idx = ((mi * 16 + lr) * K1 + k) ^ aswz;
      af[mi] = *(const bf16x8*)&smem[idx];
    }
#pragma unroll
    for (int ni = 0; ni < 4; ni++)
      bfr[ni] = *(const bf16x8*)(w1r[ni] + k);
#pragma unroll
    for (int mi = 0; mi < 4; mi++)
#pragma unroll
      for (int ni = 0; ni < 4; ni++)
        acc[mi][ni] = __builtin_amdgcn_mfma_f32_16x16x32_bf16(af[mi], bfr[ni], acc[mi][ni], 0, 0, 0);
  }
  __syncthreads();   // all waves done reading A-tile

  // ---- act + bf16 -> h-tile in same LDS (semantic [64][256], same swizzle) ----
  float bb1[4];
#pragma unroll
  for (int ni = 0; ni < 4; ni++) bb1[ni] = b1[n0 + ni * 16 + lr];
#pragma unroll
  for (int mi = 0; mi < 4; mi++)
#pragma unroll
    for (int ni = 0; ni < 4; ni++)
#pragma unroll
      for (int r = 0; r < 4; r++){
        float v = actf(acc[mi][ni][r] + bb1[ni]);
        int row = mi * 16 + lg * 4 + r;
        int idx = (row * 256 + n0 + ni * 16 + lr) ^ ((row & 7) << 3);
        smem[idx] = f2b(v);
      }
  __syncthreads();

  // ---- GEMM2: h @ W2 ----
  f32x4 acc2[4][4];
#pragma unroll
  for (int mi = 0; mi < 4; mi++)
#pragma unroll
    for (int ni = 0; ni < 4; ni++) acc2[mi][ni] = (f32x4){0.f,0.f,0.f,0.f};

  for (int ks = 0; ks < 8; ks++){
    int k = ks * 32 + lg * 8;
    bf16x8 af[4], bfr[4];
#pragma unroll
    for (int mi = 0; mi < 4; mi++){
      int idx = ((mi * 16 + lr) * 256 + k) ^ aswz;
      af[mi] = *(const bf16x8*)&smem[idx];
    }
#pragma unroll
    for (int ni = 0; ni < 4; ni++)
      bfr[ni] = *(const bf16x8*)(w2r[ni] + k);
#pragma unroll
    for (int mi = 0; mi < 4; mi++)
#pragma unroll
      for (int ni = 0; ni < 4; ni++)
        acc2[mi][ni] = __builtin_amdgcn_mfma_f32_16x16x32_bf16(af[mi], bfr[ni], acc2[mi][ni], 0, 0, 0);
  }

  // ---- epilogue: + b2 (+x), write x f32 and axb bf16 ----
  float bb2[4];
#pragma unroll
  for (int ni = 0; ni < 4; ni++) bb2[ni] = b2[n0 + ni * 16 + lr];
#pragma unroll
  for (int mi = 0; mi < 4; mi++)
#pragma unroll
    for (int r = 0; r < 4; r++){
      long row = m0 + mi * 16 + lg * 4 + r;
      if (row < nN){
#pragma unroll
        for (int ni = 0; ni < 4; ni++){
          size_t idx = (size_t)row * 256 + n0 + ni * 16 + lr;
          float v = acc2[mi][ni][r] + bb2[ni];
          if (RESID) v += x[idx];
          x[idx] = v;
          axb[idx] = f2b(actf(v));
        }
      }
    }
}

// ---------------- aggregation: single weighted-neighbor loop, unroll x8 ----------------
__global__ __launch_bounds__(256) void k_agg(
    const ushort* __restrict__ axb, ushort* __restrict__ aggb, const float* __restrict__ scale,
    const int* __restrict__ off_t, const int* __restrict__ deg_t,
    const int* __restrict__ nbr_all, const float* __restrict__ wgt_all, int nN){
  int wave = threadIdx.x >> 6;
  int lane = threadIdx.x & 63;
  int n = blockIdx.x * 4 + wave;
  if (n >= nN) return;
  const uint2* xr = (const uint2*)axb;
  float sn = scale[n];

  uint2 v = xr[(size_t)n * 64 + lane];
  float c = 2.f * sn + 1.f;
  float r0 = c * b2f((ushort)v.x), r1 = c * b2f((ushort)(v.x >> 16));
  float r2 = c * b2f((ushort)v.y), r3 = c * b2f((ushort)(v.y >> 16));

  const int o = off_t[n], d = deg_t[n];
  int i = 0;
  for (; i + 8 <= d; i += 8){
    int u[8]; float w[8];
#pragma unroll
    for (int j = 0; j < 8; j++){ u[j] = nbr_all[o + i + j]; w[j] = wgt_all[o + i + j]; }
    uint2 t[8];
#pragma unroll
    for (int j = 0; j < 8; j++) t[j] = xr[(size_t)u[j] * 64 + lane];
#pragma unroll
    for (int j = 0; j < 8; j++){
      r0 += w[j] * b2f((ushort)t[j].x); r1 += w[j] * b2f((ushort)(t[j].x >> 16));
      r2 += w[j] * b2f((ushort)t[j].y); r3 += w[j] * b2f((ushort)(t[j].y >> 16));
    }
  }
  for (; i < d; i++){
    int u = nbr_all[o + i]; float w = wgt_all[o + i];
    uint2 t = xr[(size_t)u * 64 + lane];
    r0 += w * b2f((ushort)t.x); r1 += w * b2f((ushort)(t.x >> 16));
    r2 += w * b2f((ushort)t.y); r3 += w * b2f((ushort)(t.y >> 16));
  }

  uint2 out;
  out.x = (uint)f2b(r0) | ((uint)f2b(r1) << 16);
  out.y = (uint)f2b(r2) | ((uint)f2b(r3) << 16);
  ((uint2*)aggb)[(size_t)n * 64 + lane] = out;
}

// ---------------- pooling ----------------
__global__ __launch_bounds__(256) void k_pool(const ushort* __restrict__ axb,
                                              const int* __restrict__ gids,
                                              float* __restrict__ pooled, int nN){
  int j = threadIdx.x;
  int base = blockIdx.x * 256;
  if (base >= nN) return;
  int end = base + 256; if (end > nN) end = nN;
  float acc = 0.f;
  int gcur = gids[base];
  for (int n = base; n < end; n++){
    int g = gids[n];
    if (g != gcur){
      atomicAdd(&pooled[gcur * H + j], acc);
      acc = 0.f; gcur = g;
    }
    acc += b2f(axb[(size_t)n * H + j]);
  }
  atomicAdd(&pooled[gcur * H + j], acc);
}

// ---------------- post MLP ----------------
__global__ __launch_bounds__(256) void k_post(const float* __restrict__ pooled,
                                              const float* __restrict__ W1, const float* __restrict__ b1,
                                              const float* __restrict__ W2, const float* __restrict__ b2,
                                              float* __restrict__ out){
  __shared__ float sp[H];
  __shared__ float red[256];
  int g = blockIdx.x, j = threadIdx.x;
  sp[j] = pooled[g * H + j];
  __syncthreads();
  float acc = 0.f;
  for (int k = 0; k < H; k++) acc += sp[k] * W1[k * H + j];
  acc = actf(acc + b1[j]);
  red[j] = acc * W2[j];
  __syncthreads();
  for (int s = 128; s > 0; s >>= 1){
    if (j < s) red[j] += red[j + s];
    __syncthreads();
  }
  if (j == 0) out[g] = red[0] + b2[0];
}

extern "C" void kernel_launch(void* const* d_in, const int* in_sizes, int n_in,
                              void* d_out, int out_size, void* d_ws, size_t ws_size,
                              hipStream_t stream){
  const int*   op_ids = (const int*)d_in[0];
  const int*   esrc   = (const int*)d_in[1];
  const int*   edst   = (const int*)d_in[2];
  const int*   gids   = (const int*)d_in[3];
  const float* emb    = (const float*)d_in[4];
  const float* pW1    = (const float*)d_in[5];
  const float* pb1    = (const float*)d_in[6];
  const float* pW2    = (const float*)d_in[7];
  const float* pb2    = (const float*)d_in[8];
  const float* gW1    = (const float*)d_in[9];
  const float* gb1    = (const float*)d_in[10];
  const float* gW2    = (const float*)d_in[11];
  const float* gb2    = (const float*)d_in[12];
  const float* qW1    = (const float*)d_in[13];
  const float* qb1    = (const float*)d_in[14];
  const float* qW2    = (const float*)d_in[15];
  const float* qb2    = (const float*)d_in[16];

  int nN = in_sizes[0];
  int nE = in_sizes[1];
  int nG = out_size;
  int nEmb = in_sizes[4];

  char* ws = (char*)d_ws;
  size_t off = 0;
  auto alloc = [&](size_t bytes)->char* {
    char* p = ws + off;
    off += (bytes + 255) & ~(size_t)255;
    return p;
  };
  float*  x       = (float*) alloc((size_t)nN * H * 4);
  ushort* axb     = (ushort*)alloc((size_t)nN * H * 2);
  ushort* aggb    = (ushort*)alloc((size_t)nN * H * 2);
  float*  scale   = (float*) alloc((size_t)nN * 4);
  int*    nbr_all = (int*)   alloc((size_t)2 * nE * 4);
  float*  wgt_all = (float*) alloc((size_t)2 * nE * 4);
  int*    off_t   = (int*)   alloc((size_t)nN * 4);
  ushort* embb    = (ushort*)alloc((size_t)nEmb * 2);
  ushort* wtp1    = (ushort*)alloc((size_t)64 * 256 * 2);
  ushort* wtp2    = (ushort*)alloc((size_t)256 * 256 * 2);
  ushort* wtg     = (ushort*)alloc((size_t)6 * 256 * 256 * 2);
  char*   zbase   = ws + off;
  int*    deg_s   = (int*)   alloc((size_t)nN * 4);
  int*    deg_t   = (int*)   alloc((size_t)nN * 4);
  int*    cur     = (int*)   alloc((size_t)nN * 4);
  int*    ctr     = (int*)   alloc(256);
  float*  pooled  = (float*) alloc((size_t)nG * H * 4);
  size_t zbytes = (size_t)((ws + off) - zbase);

  hipMemsetAsync(zbase, 0, zbytes, stream);

  const int tb = 256;
  k_deg<<<(nE + tb - 1)/tb, tb, 0, stream>>>(esrc, edst, deg_s, deg_t, nE);
  k_scale_off<<<(nN + tb - 1)/tb, tb, 0, stream>>>(deg_s, deg_t, scale, off_t, ctr, nN);
  k_fill<<<(nE + tb - 1)/tb, tb, 0, stream>>>(esrc, edst, scale, off_t, cur, nbr_all, wgt_all, nE);

  k_cvt<<<(nEmb + 255)/256, 256, 0, stream>>>(emb, embb, nEmb);
  k_repack<<<(64*256 + 255)/256, 256, 0, stream>>>(pW1, wtp1, 64, 256);
  k_repack<<<(256*256 + 255)/256, 256, 0, stream>>>(pW2, wtp2, 256, 256);
  for (int i = 0; i < 3; i++){
    k_repack<<<(256*256 + 255)/256, 256, 0, stream>>>(gW1 + (size_t)i*256*256, wtg + (size_t)(2*i)*256*256, 256, 256);
    k_repack<<<(256*256 + 255)/256, 256, 0, stream>>>(gW2 + (size_t)i*256*256, wtg + (size_t)(2*i+1)*256*256, 256, 256);
  }

  int gblk = (nN + 63) / 64;
  k_fused_mlp<64, false, true><<<gblk, 256, 0, stream>>>(
      embb, op_ids, wtp1, pb1, wtp2, pb2, x, axb, nN);

  for (int i = 0; i < 3; i++){
    k_agg<<<(nN + 3)/4, 256, 0, stream>>>(axb, aggb, scale, off_t, deg_t, nbr_all, wgt_all, nN);
    k_fused_mlp<256, true, false><<<gblk, 256, 0, stream>>>(
        aggb, op_ids, wtg + (size_t)(2*i)*256*256, gb1 + (size_t)i*H,
        wtg + (size_t)(2*i+1)*256*256, gb2 + (size_t)i*H, x, axb, nN);
  }

  k_pool<<<(nN + 255)/256, 256, 0, stream>>>(axb, gids, pooled, nN);
  k_post<<<nG, 256, 0, stream>>>(pooled, qW1, qb1, qW2, qb2, (float*)d_out);
}